// Round 6
// baseline (1146.473 us; speedup 1.0000x reference)
//
#include <hip/hip_runtime.h>
#include <hip/hip_bf16.h>
#include <hip/hip_cooperative_groups.h>

namespace cg = cooperative_groups;

#define N_NODES 10000
#define N_EDGES 320000
#define HDIM    256
#define NCLS    40
#define NBLK    512

typedef __attribute__((ext_vector_type(8))) short short8;
typedef __attribute__((ext_vector_type(4))) float floatx4;
typedef unsigned long long ull;
typedef unsigned short ushort;

__device__ __forceinline__ float bf2f(ushort u) {
    union { unsigned int i; float f; } v; v.i = ((unsigned int)u) << 16; return v.f;
}
__device__ __forceinline__ ushort f2bf(float f) {
    __hip_bfloat16 h = __float2bfloat16(f);
    return *reinterpret_cast<ushort*>(&h);
}

struct Args {
    const void* x;
    const void* ei;
    const void* wsrc[10];
    ushort* wdst[10];
    int woffs[11];
    ushort* wb[5];
    ushort* bb[5];
    ushort* xb;
    int* src32; int* dst32; int* cnt; int* offs; int* woff;
    float* dinv; int* csr;
    ushort* tbuf; ushort* hbuf; float* t5;
    void* out; int* flags;
};

#define PREP_XB 2500
#define PREP_WB 1069
#define PREP_EB 1250
#define PREP_ZB 40
#define PREP_SB 1
#define PREP_TOTAL (PREP_XB + PREP_WB + PREP_EB + PREP_ZB + PREP_SB)
#define WTOT 273448

__device__ __forceinline__ void accum16(float* acc, int4 r) {
#pragma unroll
    for (int k = 0; k < 4; ++k) {
        union { int i; float f; } lo, hi;
        int d = (&r.x)[k];
        lo.i = d << 16;
        hi.i = d & 0xffff0000;
        acc[2 * k]     += lo.f;
        acc[2 * k + 1] += hi.f;
    }
}

// ================= phase bodies (shared by mega + fallback) =================

__device__ __forceinline__ void detect_body(const Args& a, int lane) {
    const ushort* u = (const ushort*)a.x;
    int e = (u[2 * lane] >> 7) & 0xFF;
    ull badmask = __ballot(e < 100 || e > 140);
    const int* ii = (const int*)a.ei;
    ull oddnz = __ballot(ii[2 * lane + 1] != 0);
    if (lane == 0) {
        a.flags[0] = (__popcll(badmask) >= 8) ? 1 : 0;
        a.flags[1] = (oddnz == 0) ? 1 : 0;
    }
}

__device__ __forceinline__ void prep_body(const Args& a, int b, int tid, int f32, int i64) {
    if (b < PREP_XB) {
        int i4 = b * 256 + tid;      // 2500*256 vec4 == 2,560,000 elements exactly
        if (f32) {
            float4 v = ((const float4*)a.x)[i4];
            ull p = (ull)f2bf(v.x) | ((ull)f2bf(v.y) << 16) |
                    ((ull)f2bf(v.z) << 32) | ((ull)f2bf(v.w) << 48);
            ((ull*)a.xb)[i4] = p;
        } else {
            ((ull*)a.xb)[i4] = ((const ull*)a.x)[i4];
        }
    } else if (b < PREP_XB + PREP_WB) {
        int i = (b - PREP_XB) * 256 + tid;
        if (i < WTOT) {
            int t = 0;
#pragma unroll
            for (int k = 1; k < 10; ++k) t += (i >= a.woffs[k]);
            int local = i - a.woffs[t];
            ushort v;
            if (f32) v = f2bf(((const float*)a.wsrc[t])[local]);
            else     v = ((const ushort*)a.wsrc[t])[local];
            a.wdst[t][local] = v;
        }
    } else if (b < PREP_XB + PREP_WB + PREP_EB) {
        int e = (b - PREP_XB - PREP_WB) * 256 + tid;
        const int* ii = (const int*)a.ei;
        int s, d;
        if (i64) { s = ii[2 * e]; d = ii[2 * (N_EDGES + e)]; }
        else     { s = ii[e];     d = ii[N_EDGES + e]; }
        a.src32[e] = ((unsigned)s < N_NODES) ? s : 0;
        a.dst32[e] = ((unsigned)d < N_NODES) ? d : 0;
    } else if (b < PREP_XB + PREP_WB + PREP_EB + PREP_ZB) {
        int i = (b - PREP_XB - PREP_WB - PREP_EB) * 256 + tid;
        if (i < N_NODES) a.cnt[i] = 0;
    } else {
        if (tid < 64)       ((ull*)(a.tbuf + (size_t)N_NODES * 256))[tid] = 0;
        else if (tid < 128) ((ull*)(a.hbuf + (size_t)N_NODES * 256))[tid - 64] = 0;
    }
}

__device__ __forceinline__ void scan_body(const Args& a, int tid, int* part) {
    const int CH = 40;  // 256*40 >= 10000
    const int base = tid * CH;
    int s = 0;
    for (int j = 0; j < CH; ++j) {
        int i = base + j;
        if (i < N_NODES) s += a.cnt[i];
    }
    part[tid] = s;
    __syncthreads();
    for (int off = 1; off < 256; off <<= 1) {
        int v = (tid >= off) ? part[tid - off] : 0;
        __syncthreads();
        part[tid] += v;
        __syncthreads();
    }
    int run = (tid == 0) ? 0 : part[tid - 1];
    for (int j = 0; j < CH; ++j) {
        int i = base + j;
        if (i < N_NODES) {
            int c = a.cnt[i];
            a.offs[i] = run;
            a.woff[i] = run;
            a.dinv[i] = rsqrtf((float)c + 1.0f);
            run += c;
        }
    }
}

// gemm256 streams: col tile c0 (32 cols), row-tile stream rt0 with stride rtstep
__device__ __forceinline__ void gemm256_body(const ushort* __restrict__ A,
                                             const ushort* __restrict__ W,
                                             const float* __restrict__ dinv,
                                             ushort* __restrict__ T,
                                             int c0, int rt0, int rtstep,
                                             int m, int quad) {
    short8 bfrag[2][8];
#pragma unroll
    for (int t = 0; t < 2; ++t)
#pragma unroll
        for (int s = 0; s < 8; ++s)
#pragma unroll
            for (int j = 0; j < 8; ++j)
                bfrag[t][s][j] = (short)W[(size_t)(s * 32 + quad * 8 + j) * 256 + c0 + t * 16 + m];

    for (int rt = rt0; rt < N_NODES / 16; rt += rtstep) {
        const int r0 = rt * 16;
        floatx4 acc0 = {0.f, 0.f, 0.f, 0.f};
        floatx4 acc1 = {0.f, 0.f, 0.f, 0.f};
        const ushort* arow = A + (size_t)(r0 + m) * 256 + quad * 8;
#pragma unroll
        for (int s = 0; s < 8; ++s) {
            short8 af = *(const short8*)(arow + s * 32);
            acc0 = __builtin_amdgcn_mfma_f32_16x16x32_bf16(af, bfrag[0][s], acc0, 0, 0, 0);
            acc1 = __builtin_amdgcn_mfma_f32_16x16x32_bf16(af, bfrag[1][s], acc1, 0, 0, 0);
        }
#pragma unroll
        for (int r = 0; r < 4; ++r) {
            int row = r0 + quad * 4 + r;
            float di = dinv[row];
            T[(size_t)row * 256 + c0 + m]      = f2bf(acc0[r] * di);
            T[(size_t)row * 256 + c0 + 16 + m] = f2bf(acc1[r] * di);
        }
    }
}

__device__ __forceinline__ void gemm40_body(const ushort* __restrict__ A,
                                            const ushort* __restrict__ W,
                                            const float* __restrict__ dinv,
                                            float* __restrict__ T,
                                            int colblk, int rt0, int rtstep,
                                            int m, int quad) {
    const int col = colblk * 16 + m;
    const bool colok = col < NCLS;
    short8 bfrag[8];
#pragma unroll
    for (int s = 0; s < 8; ++s)
#pragma unroll
        for (int j = 0; j < 8; ++j)
            bfrag[s][j] = colok ? (short)W[(size_t)(s * 32 + quad * 8 + j) * NCLS + col] : (short)0;

    for (int rt = rt0; rt < N_NODES / 16; rt += rtstep) {
        const int r0 = rt * 16;
        floatx4 acc = {0.f, 0.f, 0.f, 0.f};
        const ushort* arow = A + (size_t)(r0 + m) * 256 + quad * 8;
#pragma unroll
        for (int s = 0; s < 8; ++s) {
            short8 af = *(const short8*)(arow + s * 32);
            acc = __builtin_amdgcn_mfma_f32_16x16x32_bf16(af, bfrag[s], acc, 0, 0, 0);
        }
        if (colok) {
#pragma unroll
            for (int r = 0; r < 4; ++r) {
                int row = r0 + quad * 4 + r;
                T[(size_t)row * NCLS + col] = acc[r] * dinv[row];
            }
        }
    }
}

__device__ __forceinline__ void agg256_node(const Args& a, const ushort* __restrict__ T,
                                            const ushort* __restrict__ bias,
                                            int node, int lane) {
    const int half = lane >> 5;
    const int q = lane & 31;
    const int start = a.offs[node];
    const int count = a.cnt[node];
    const float di = a.dinv[node];

    float acc[8];
    {
        int sinit = half ? N_NODES : node;
        int4 r = *(const int4*)(T + (size_t)sinit * 256 + q * 8);
#pragma unroll
        for (int k = 0; k < 4; ++k) {
            union { int i; float f; } lo, hi;
            int d = (&r.x)[k];
            lo.i = d << 16; hi.i = d & 0xffff0000;
            acc[2 * k] = lo.f; acc[2 * k + 1] = hi.f;
        }
    }

    for (int bj = 0; bj < count; bj += 64) {
        int mrem = count - bj;
        int mm = mrem < 64 ? mrem : 64;
        int idxv = (lane < mm) ? a.csr[start + bj + lane] : N_NODES;
        int j2 = 0;
        for (; j2 + 16 <= mm; j2 += 16) {
            int s[8];
#pragma unroll
            for (int k = 0; k < 8; ++k) s[k] = __shfl(idxv, j2 + 2 * k + half);
            int4 r[8];
#pragma unroll
            for (int k = 0; k < 8; ++k) r[k] = *(const int4*)(T + (size_t)s[k] * 256 + q * 8);
#pragma unroll
            for (int k = 0; k < 8; ++k) accum16(acc, r[k]);
        }
        for (; j2 < mm; j2 += 2) {
            int s = __shfl(idxv, j2 + half);
            int4 r = *(const int4*)(T + (size_t)s * 256 + q * 8);
            accum16(acc, r);
        }
    }

#pragma unroll
    for (int i = 0; i < 8; ++i) acc[i] += __shfl_xor(acc[i], 32);

    if (half == 0) {
        int4 bv = *(const int4*)(bias + q * 8);
        int out_d[4];
#pragma unroll
        for (int k = 0; k < 4; ++k) {
            union { int i; float f; } lo, hi;
            int d = (&bv.x)[k];
            lo.i = d << 16; hi.i = d & 0xffff0000;
            float v0 = fmaxf(acc[2 * k] * di + lo.f, 0.f);
            float v1 = fmaxf(acc[2 * k + 1] * di + hi.f, 0.f);
            out_d[k] = (int)f2bf(v0) | ((int)f2bf(v1) << 16);
        }
        *(int4*)(a.hbuf + (size_t)node * 256 + q * 8) = *(int4*)out_d;
    }
}

__device__ __forceinline__ void aggsoft_node(const Args& a, int node, int lane, int f32) {
    const float* T = a.t5;
    const ushort* bias = a.bb[4];
    const int start = a.offs[node];
    const int count = a.cnt[node];
    const float di = a.dinv[node];

    float acc = (lane < NCLS) ? T[(size_t)node * NCLS + lane] : 0.f;
    for (int bj = 0; bj < count; bj += 64) {
        int mrem = count - bj;
        int mm = mrem < 64 ? mrem : 64;
        int idxv = (lane < mm) ? a.csr[start + bj + lane] : 0;
        int jj = 0;
        for (; jj + 4 <= mm; jj += 4) {
            int s0 = __shfl(idxv, jj + 0);
            int s1 = __shfl(idxv, jj + 1);
            int s2 = __shfl(idxv, jj + 2);
            int s3 = __shfl(idxv, jj + 3);
            if (lane < NCLS) {
                float t0 = T[(size_t)s0 * NCLS + lane];
                float t1 = T[(size_t)s1 * NCLS + lane];
                float t2 = T[(size_t)s2 * NCLS + lane];
                float t3 = T[(size_t)s3 * NCLS + lane];
                acc += t0 + t1 + t2 + t3;
            }
        }
        for (; jj < mm; ++jj) {
            int s = __shfl(idxv, jj);
            if (lane < NCLS) acc += T[(size_t)s * NCLS + lane];
        }
    }

    float l5 = (lane < NCLS) ? (acc * di + bf2f(bias[lane])) : -INFINITY;
    float mx = l5;
#pragma unroll
    for (int o = 32; o > 0; o >>= 1) mx = fmaxf(mx, __shfl_xor(mx, o));
    float e = (lane < NCLS) ? __expf(l5 - mx) : 0.f;
    float sum = e;
#pragma unroll
    for (int o = 32; o > 0; o >>= 1) sum += __shfl_xor(sum, o);
    float ls = l5 - mx - __logf(sum);
    if (lane < NCLS) {
        size_t i0 = (size_t)node * NCLS + lane;
        size_t i1 = (size_t)N_NODES * NCLS + i0;
        if (f32) {
            ((float*)a.out)[i0] = ls;
            ((float*)a.out)[i1] = l5;
        } else {
            ((ushort*)a.out)[i0] = f2bf(ls);
            ((ushort*)a.out)[i1] = f2bf(l5);
        }
    }
}

// ================= mega kernel (cooperative) =================

__global__ __launch_bounds__(256, 2)
void mega_kernel(Args a) {
    cg::grid_group grid = cg::this_grid();
    __shared__ int part[256];

    const int bid = blockIdx.x;
    const int nb = gridDim.x;
    const int tid = threadIdx.x;
    const int lane = tid & 63;
    const int wave = tid >> 6;
    const int m = lane & 15;
    const int quad = lane >> 4;

    if (bid == 0 && tid < 64) detect_body(a, lane);
    grid.sync();

    const int f32 = a.flags[0];
    const int i64 = a.flags[1];

    for (int b = bid; b < PREP_TOTAL; b += nb) prep_body(a, b, tid, f32, i64);
    grid.sync();

    for (int e = bid * 256 + tid; e < N_EDGES; e += nb * 256)
        atomicAdd(&a.cnt[a.dst32[e]], 1);
    grid.sync();

    if (bid == 0) scan_body(a, tid, part);
    grid.sync();

    for (int e = bid * 256 + tid; e < N_EDGES; e += nb * 256) {
        int d = a.dst32[e];
        int p = atomicAdd(&a.woff[d], 1);
        a.csr[p] = a.src32[e];
    }
    grid.sync();

    for (int l = 0; l < 4; ++l) {
        const ushort* A = (l == 0) ? a.xb : a.hbuf;
        gemm256_body(A, a.wb[l], a.dinv, a.tbuf,
                     (bid & 7) * 32, (bid >> 3) * 4 + wave, (NBLK / 8) * 4, m, quad);
        grid.sync();
        for (int g4 = bid; g4 < N_NODES / 4; g4 += nb)
            agg256_node(a, a.tbuf, a.bb[l], g4 * 4 + wave, lane);
        grid.sync();
    }

    gemm40_body(a.hbuf, a.wb[4], a.dinv, a.t5,
                bid % 3, (bid / 3) * 4 + wave, ((NBLK + 2) / 3) * 4, m, quad);
    grid.sync();

    for (int g4 = bid; g4 < N_NODES / 4; g4 += nb)
        aggsoft_node(a, g4 * 4 + wave, lane, f32);
}

// ================= fallback kernels (round-4 structure) =================

__global__ void detect_kernel(Args a) { if (threadIdx.x < 64) detect_body(a, threadIdx.x & 63); }

__global__ __launch_bounds__(256)
void prep_kernel(Args a) { prep_body(a, blockIdx.x, threadIdx.x, a.flags[0], a.flags[1]); }

__global__ void count_kernel(Args a) {
    int e = blockIdx.x * 256 + threadIdx.x;
    if (e < N_EDGES) atomicAdd(&a.cnt[a.dst32[e]], 1);
}

__global__ __launch_bounds__(256)
void scan_kernel(Args a) { __shared__ int part[256]; scan_body(a, threadIdx.x, part); }

__global__ void fill_kernel(Args a) {
    int e = blockIdx.x * 256 + threadIdx.x;
    if (e < N_EDGES) {
        int d = a.dst32[e];
        int p = atomicAdd(&a.woff[d], 1);
        a.csr[p] = a.src32[e];
    }
}

__global__ __launch_bounds__(256)
void gemm256_kernel(Args a, int l) {
    const int lane = threadIdx.x & 63;
    const ushort* A = (l == 0) ? a.xb : a.hbuf;
    gemm256_body(A, a.wb[l], a.dinv, a.tbuf, blockIdx.x * 32,
                 blockIdx.y * 4 + (threadIdx.x >> 6), gridDim.y * 4,
                 lane & 15, lane >> 4);
}

__global__ __launch_bounds__(256)
void agg256_kernel(Args a, int l) {
    agg256_node(a, a.tbuf, a.bb[l], blockIdx.x * 4 + (threadIdx.x >> 6), threadIdx.x & 63);
}

__global__ __launch_bounds__(256)
void gemm40_kernel(Args a) {
    const int lane = threadIdx.x & 63;
    gemm40_body(a.hbuf, a.wb[4], a.dinv, a.t5, blockIdx.x,
                blockIdx.y * 4 + (threadIdx.x >> 6), gridDim.y * 4,
                lane & 15, lane >> 4);
}

__global__ __launch_bounds__(256)
void aggsoft_kernel(Args a) {
    aggsoft_node(a, blockIdx.x * 4 + (threadIdx.x >> 6), threadIdx.x & 63, a.flags[0]);
}

// ================= host =================

static inline size_t alup(size_t x) { return (x + 255) & ~(size_t)255; }

extern "C" void kernel_launch(void* const* d_in, const int* in_sizes, int n_in,
                              void* d_out, int out_size, void* d_ws, size_t ws_size,
                              hipStream_t stream) {
    char* w = (char*)d_ws;
    int* flags   = (int*)w;           w += alup(16);
    float* dinv  = (float*)w;         w += alup(N_NODES * 4);
    int* cnt     = (int*)w;           w += alup(N_NODES * 4);
    int* offs    = (int*)w;           w += alup(N_NODES * 4);
    int* woff    = (int*)w;           w += alup(N_NODES * 4);
    int* src32   = (int*)w;           w += alup(N_EDGES * 4);
    int* dst32   = (int*)w;           w += alup(N_EDGES * 4);
    int* csr     = (int*)w;           w += alup(N_EDGES * 4);
    ushort* xb   = (ushort*)w;        w += alup((size_t)N_NODES * HDIM * 2);
    ushort* wb[5]; ushort* bb[5];
    for (int l = 0; l < 5; ++l) {
        int wn = (l < 4) ? HDIM * HDIM : HDIM * NCLS;
        int bn = (l < 4) ? HDIM : NCLS;
        wb[l] = (ushort*)w; w += alup((size_t)wn * 2);
        bb[l] = (ushort*)w; w += alup((size_t)bn * 2);
    }
    ushort* tbuf = (ushort*)w;        w += alup((size_t)(N_NODES + 16) * HDIM * 2);
    ushort* hbuf = (ushort*)w;        w += alup((size_t)(N_NODES + 16) * HDIM * 2);
    float* t5    = (float*)w;         w += alup((size_t)N_NODES * NCLS * 4);

    Args a;
    a.x = d_in[0];
    a.ei = d_in[1];
    int sizes[10] = { HDIM * HDIM, HDIM, HDIM * HDIM, HDIM, HDIM * HDIM, HDIM,
                      HDIM * HDIM, HDIM, HDIM * NCLS, NCLS };
    int run = 0;
    for (int t = 0; t < 10; ++t) {
        a.wsrc[t] = d_in[2 + t];
        a.wdst[t] = (t & 1) ? bb[t >> 1] : wb[t >> 1];
        a.woffs[t] = run;
        run += sizes[t];
    }
    a.woffs[10] = run;  // == WTOT
    for (int l = 0; l < 5; ++l) { a.wb[l] = wb[l]; a.bb[l] = bb[l]; }
    a.xb = xb; a.src32 = src32; a.dst32 = dst32; a.cnt = cnt;
    a.offs = offs; a.woff = woff; a.dinv = dinv; a.csr = csr;
    a.tbuf = tbuf; a.hbuf = hbuf; a.t5 = t5;
    a.out = d_out; a.flags = flags;

    Args acopy = a;
    void* params[1] = { &acopy };
    hipError_t err = hipLaunchCooperativeKernel((const void*)mega_kernel, dim3(NBLK),
                                                dim3(256), params, 0, stream);
    if (err != hipSuccess) {
        // fallback: proven multi-kernel pipeline (identical numerics)
        const int eblk = (N_EDGES + 255) / 256;   // 1250
        const int aggblk = N_NODES / 4;           // 2500
        detect_kernel<<<1, 64, 0, stream>>>(a);
        prep_kernel<<<PREP_TOTAL, 256, 0, stream>>>(a);
        count_kernel<<<eblk, 256, 0, stream>>>(a);
        scan_kernel<<<1, 256, 0, stream>>>(a);
        fill_kernel<<<eblk, 256, 0, stream>>>(a);
        for (int l = 0; l < 4; ++l) {
            gemm256_kernel<<<dim3(8, 78), 256, 0, stream>>>(a, l);
            agg256_kernel<<<aggblk, 256, 0, stream>>>(a, l);
        }
        gemm40_kernel<<<dim3(3, 80), 256, 0, stream>>>(a);
        aggsoft_kernel<<<aggblk, 256, 0, stream>>>(a);
    }
}

// Round 7
// 316.611 us; speedup vs baseline: 3.6211x; 3.6211x over previous
//
#include <hip/hip_runtime.h>
#include <hip/hip_bf16.h>

#define N_NODES 10000
#define N_EDGES 320000
#define HDIM    256
#define NCLS    40

typedef __attribute__((ext_vector_type(8))) short short8;
typedef __attribute__((ext_vector_type(4))) float floatx4;
typedef unsigned long long ull;
typedef unsigned short ushort;

__device__ __forceinline__ float bf2f(ushort u) {
    union { unsigned int i; float f; } v; v.i = ((unsigned int)u) << 16; return v.f;
}
__device__ __forceinline__ ushort f2bf(float f) {
    __hip_bfloat16 h = __float2bfloat16(f);
    return *reinterpret_cast<ushort*>(&h);
}

// ---------------- dtype detection: flags[0]=fp32 floats, flags[1]=int64 edges ----------------

__global__ void detect_kernel(const void* x, const void* ei, int* flags) {
    const int lane = threadIdx.x & 63;
    const ushort* u = (const ushort*)x;
    int e = (u[2 * lane] >> 7) & 0xFF;
    ull badmask = __ballot(e < 100 || e > 140);
    const int* ii = (const int*)ei;
    ull oddnz = __ballot(ii[2 * lane + 1] != 0);
    if (lane == 0) {
        flags[0] = (__popcll(badmask) >= 8) ? 1 : 0;
        flags[1] = (oddnz == 0) ? 1 : 0;
    }
}

// ---------------- fused prep ----------------

struct PrepArgs {
    const void* x;
    const void* ei;
    const void* wsrc[10];
    ushort* wdst[10];
    int woffs[11];
    ushort* xb;
    int* src32;
    int* dst32;
    int* cnt;
    ushort* tbuf;   // sentinel row zeroing
    ushort* hbuf;
    const int* flags;
};

#define PREP_XB 2500
#define PREP_WB 1069
#define PREP_EB 1250
#define PREP_ZB 40
#define PREP_SB 1
#define PREP_TOTAL (PREP_XB + PREP_WB + PREP_EB + PREP_ZB + PREP_SB)
#define WTOT 273448

__global__ __launch_bounds__(256)
void prep_kernel(PrepArgs a) {
    const int b = blockIdx.x;
    const int f32 = a.flags[0];
    if (b < PREP_XB) {
        int i4 = b * 256 + threadIdx.x;   // 2500*256 vec4 == 2,560,000 elements exactly
        if (f32) {
            float4 v = ((const float4*)a.x)[i4];
            ull p = (ull)f2bf(v.x) | ((ull)f2bf(v.y) << 16) |
                    ((ull)f2bf(v.z) << 32) | ((ull)f2bf(v.w) << 48);
            ((ull*)a.xb)[i4] = p;
        } else {
            ((ull*)a.xb)[i4] = ((const ull*)a.x)[i4];
        }
    } else if (b < PREP_XB + PREP_WB) {
        int i = (b - PREP_XB) * 256 + threadIdx.x;
        if (i < WTOT) {
            int t = 0;
#pragma unroll
            for (int k = 1; k < 10; ++k) t += (i >= a.woffs[k]);
            int local = i - a.woffs[t];
            ushort v;
            if (f32) v = f2bf(((const float*)a.wsrc[t])[local]);
            else     v = ((const ushort*)a.wsrc[t])[local];
            a.wdst[t][local] = v;
        }
    } else if (b < PREP_XB + PREP_WB + PREP_EB) {
        int e = (b - PREP_XB - PREP_WB) * 256 + threadIdx.x;
        const int* ii = (const int*)a.ei;
        int s, d;
        if (a.flags[1]) { s = ii[2 * e]; d = ii[2 * (N_EDGES + e)]; }
        else            { s = ii[e];     d = ii[N_EDGES + e]; }
        a.src32[e] = ((unsigned)s < N_NODES) ? s : 0;
        a.dst32[e] = ((unsigned)d < N_NODES) ? d : 0;
    } else if (b < PREP_XB + PREP_WB + PREP_EB + PREP_ZB) {
        int i = (b - PREP_XB - PREP_WB - PREP_EB) * 256 + threadIdx.x;
        if (i < N_NODES) a.cnt[i] = 0;
    } else {
        int t = threadIdx.x;
        if (t < 64)       ((ull*)(a.tbuf + (size_t)N_NODES * 256))[t] = 0;
        else if (t < 128) ((ull*)(a.hbuf + (size_t)N_NODES * 256))[t - 64] = 0;
    }
}

// ---------------- CSR build ----------------

__global__ void count_kernel(const int* __restrict__ dst, int* __restrict__ cnt) {
    int e = blockIdx.x * 256 + threadIdx.x;
    if (e < N_EDGES) atomicAdd(&cnt[dst[e]], 1);
}

__global__ __launch_bounds__(256)
void scan_dinv_kernel(const int* __restrict__ cnt, int* __restrict__ offs,
                      int* __restrict__ woff, float* __restrict__ dinv) {
    __shared__ int part[256];
    const int t = threadIdx.x;
    const int CH = 40;  // 256*40 >= 10000
    const int base = t * CH;
    int s = 0;
    for (int j = 0; j < CH; ++j) {
        int i = base + j;
        if (i < N_NODES) s += cnt[i];
    }
    part[t] = s;
    __syncthreads();
    for (int off = 1; off < 256; off <<= 1) {
        int v = (t >= off) ? part[t - off] : 0;
        __syncthreads();
        part[t] += v;
        __syncthreads();
    }
    int run = (t == 0) ? 0 : part[t - 1];
    for (int j = 0; j < CH; ++j) {
        int i = base + j;
        if (i < N_NODES) {
            int c = cnt[i];
            offs[i] = run;
            woff[i] = run;
            dinv[i] = rsqrtf((float)c + 1.0f);
            run += c;
        }
    }
}

__global__ void fill_kernel(const int* __restrict__ src, const int* __restrict__ dst,
                            int* __restrict__ woff, int* __restrict__ csr) {
    int e = blockIdx.x * 256 + threadIdx.x;
    if (e < N_EDGES) {
        int d = dst[e];
        int p = atomicAdd(&woff[d], 1);
        csr[p] = src[e];
    }
}

// ---------------- GEMM 256-wide: 2 col-tiles per wave, grid (8, 78) ----------------

__global__ __launch_bounds__(256)
void gemm256_kernel(const ushort* __restrict__ A, const ushort* __restrict__ W,
                    const float* __restrict__ dinv, ushort* __restrict__ T) {
    const int lane = threadIdx.x & 63;
    const int wave = threadIdx.x >> 6;
    const int m = lane & 15;
    const int quad = lane >> 4;
    const int c0 = blockIdx.x * 32;

    short8 bfrag[2][8];
#pragma unroll
    for (int t = 0; t < 2; ++t)
#pragma unroll
        for (int s = 0; s < 8; ++s)
#pragma unroll
            for (int j = 0; j < 8; ++j)
                bfrag[t][s][j] = (short)W[(size_t)(s * 32 + quad * 8 + j) * 256 + c0 + t * 16 + m];

    const int step = gridDim.y * 4;
    for (int rt = blockIdx.y * 4 + wave; rt < N_NODES / 16; rt += step) {
        const int r0 = rt * 16;
        floatx4 acc0 = {0.f, 0.f, 0.f, 0.f};
        floatx4 acc1 = {0.f, 0.f, 0.f, 0.f};
        const ushort* arow = A + (size_t)(r0 + m) * 256 + quad * 8;
#pragma unroll
        for (int s = 0; s < 8; ++s) {
            short8 af = *(const short8*)(arow + s * 32);
            acc0 = __builtin_amdgcn_mfma_f32_16x16x32_bf16(af, bfrag[0][s], acc0, 0, 0, 0);
            acc1 = __builtin_amdgcn_mfma_f32_16x16x32_bf16(af, bfrag[1][s], acc1, 0, 0, 0);
        }
#pragma unroll
        for (int r = 0; r < 4; ++r) {
            int row = r0 + quad * 4 + r;
            float di = dinv[row];
            T[(size_t)row * 256 + c0 + m]      = f2bf(acc0[r] * di);
            T[(size_t)row * 256 + c0 + 16 + m] = f2bf(acc1[r] * di);
        }
    }
}

// ---------------- GEMM 40-wide -> fp32 T5, grid (3, 80) ----------------

__global__ __launch_bounds__(256)
void gemm40_kernel(const ushort* __restrict__ A, const ushort* __restrict__ W,
                   const float* __restrict__ dinv, float* __restrict__ T) {
    const int lane = threadIdx.x & 63;
    const int wave = threadIdx.x >> 6;
    const int m = lane & 15;
    const int quad = lane >> 4;
    const int col = blockIdx.x * 16 + m;
    const bool colok = col < NCLS;

    short8 bfrag[8];
#pragma unroll
    for (int s = 0; s < 8; ++s)
#pragma unroll
        for (int j = 0; j < 8; ++j)
            bfrag[s][j] = colok ? (short)W[(size_t)(s * 32 + quad * 8 + j) * NCLS + col] : (short)0;

    const int step = gridDim.y * 4;
    for (int rt = blockIdx.y * 4 + wave; rt < N_NODES / 16; rt += step) {
        const int r0 = rt * 16;
        floatx4 acc = {0.f, 0.f, 0.f, 0.f};
        const ushort* arow = A + (size_t)(r0 + m) * 256 + quad * 8;
#pragma unroll
        for (int s = 0; s < 8; ++s) {
            short8 af = *(const short8*)(arow + s * 32);
            acc = __builtin_amdgcn_mfma_f32_16x16x32_bf16(af, bfrag[s], acc, 0, 0, 0);
        }
        if (colok) {
#pragma unroll
            for (int r = 0; r < 4; ++r) {
                int row = r0 + quad * 4 + r;
                T[(size_t)row * NCLS + col] = acc[r] * dinv[row];
            }
        }
    }
}

// ---------------- Aggregation 256-wide, column-split (grid 2500 x 2) ----------------
// Pass h covers cols [h*128, h*128+128). Quarter-wave (16 lanes) per row, 16 B/lane;
// 4 rows per round, depth-8 pipeline = 8 outstanding loads/lane.

__device__ __forceinline__ void accum16(float* acc, int4 r) {
#pragma unroll
    for (int k = 0; k < 4; ++k) {
        union { int i; float f; } lo, hi;
        int d = (&r.x)[k];
        lo.i = d << 16;
        hi.i = d & 0xffff0000;
        acc[2 * k]     += lo.f;
        acc[2 * k + 1] += hi.f;
    }
}

__global__ __launch_bounds__(256)
void agg256_kernel(const ushort* __restrict__ T,
                   const int* __restrict__ csr, const int* __restrict__ offs,
                   const int* __restrict__ cnt, const float* __restrict__ dinv,
                   const ushort* __restrict__ bias,
                   ushort* __restrict__ H) {
    const int node = blockIdx.x * 4 + (threadIdx.x >> 6);
    const int lane = threadIdx.x & 63;
    const int qw = lane >> 4;        // quarter-wave 0..3
    const int q  = lane & 15;        // 16B chunk within 256B half-row
    const int h  = blockIdx.y;
    const ushort* Tb = T + h * 128 + q * 8;
    const int start = offs[node];
    const int count = cnt[node];
    const float di = dinv[node];

    float acc[8];
    {
        int sinit = (qw == 0) ? node : N_NODES;   // sentinel row = zeros
        int4 r = *(const int4*)(Tb + (size_t)sinit * 256);
#pragma unroll
        for (int k = 0; k < 4; ++k) {
            union { int i; float f; } lo, hi;
            int d = (&r.x)[k];
            lo.i = d << 16; hi.i = d & 0xffff0000;
            acc[2 * k] = lo.f; acc[2 * k + 1] = hi.f;
        }
    }

    for (int bj = 0; bj < count; bj += 64) {
        int mrem = count - bj;
        int mm = mrem < 64 ? mrem : 64;
        int idxv = (lane < mm) ? csr[start + bj + lane] : N_NODES;
        int j2 = 0;
        for (; j2 + 32 <= mm; j2 += 32) {
            int s[8];
#pragma unroll
            for (int k = 0; k < 8; ++k) s[k] = __shfl(idxv, j2 + 4 * k + qw);
            int4 r[8];
#pragma unroll
            for (int k = 0; k < 8; ++k) r[k] = *(const int4*)(Tb + (size_t)s[k] * 256);
#pragma unroll
            for (int k = 0; k < 8; ++k) accum16(acc, r[k]);
        }
        for (; j2 < mm; j2 += 4) {
            int sl = __shfl(idxv, (j2 + qw) & 63);
            int s = (j2 + qw < 64) ? sl : N_NODES;  // lanes in [mm,64) already hold sentinel
            int4 r = *(const int4*)(Tb + (size_t)s * 256);
            accum16(acc, r);
        }
    }

#pragma unroll
    for (int i = 0; i < 8; ++i) {
        acc[i] += __shfl_xor(acc[i], 16);
        acc[i] += __shfl_xor(acc[i], 32);
    }

    if (qw == 0) {
        int4 bv = *(const int4*)(bias + h * 128 + q * 8);
        int out_d[4];
#pragma unroll
        for (int k = 0; k < 4; ++k) {
            union { int i; float f; } lo, hi;
            int d = (&bv.x)[k];
            lo.i = d << 16; hi.i = d & 0xffff0000;
            float v0 = fmaxf(acc[2 * k] * di + lo.f, 0.f);
            float v1 = fmaxf(acc[2 * k + 1] * di + hi.f, 0.f);
            out_d[k] = (int)f2bf(v0) | ((int)f2bf(v1) << 16);
        }
        *(int4*)(H + (size_t)node * 256 + h * 128 + q * 8) = *(int4*)out_d;
    }
}

// ---------------- Aggregation 40-wide + log_softmax + output writes, fused ----------------

__global__ __launch_bounds__(256)
void aggsoft_kernel(const float* __restrict__ T,
                    const int* __restrict__ csr, const int* __restrict__ offs,
                    const int* __restrict__ cnt, const float* __restrict__ dinv,
                    const ushort* __restrict__ bias,
                    void* __restrict__ out, const int* __restrict__ flags) {
    const int node = blockIdx.x * 4 + (threadIdx.x >> 6);
    const int lane = threadIdx.x & 63;
    const int start = offs[node];
    const int count = cnt[node];
    const float di = dinv[node];

    float acc = (lane < NCLS) ? T[(size_t)node * NCLS + lane] : 0.f;
    for (int bj = 0; bj < count; bj += 64) {
        int mrem = count - bj;
        int mm = mrem < 64 ? mrem : 64;
        int idxv = (lane < mm) ? csr[start + bj + lane] : 0;
        int jj = 0;
        for (; jj + 4 <= mm; jj += 4) {
            int s0 = __shfl(idxv, jj + 0);
            int s1 = __shfl(idxv, jj + 1);
            int s2 = __shfl(idxv, jj + 2);
            int s3 = __shfl(idxv, jj + 3);
            if (lane < NCLS) {
                float t0 = T[(size_t)s0 * NCLS + lane];
                float t1 = T[(size_t)s1 * NCLS + lane];
                float t2 = T[(size_t)s2 * NCLS + lane];
                float t3 = T[(size_t)s3 * NCLS + lane];
                acc += t0 + t1 + t2 + t3;
            }
        }
        for (; jj < mm; ++jj) {
            int s = __shfl(idxv, jj);
            if (lane < NCLS) acc += T[(size_t)s * NCLS + lane];
        }
    }

    float l = (lane < NCLS) ? (acc * di + bf2f(bias[lane])) : -INFINITY;
    float mx = l;
#pragma unroll
    for (int o = 32; o > 0; o >>= 1) mx = fmaxf(mx, __shfl_xor(mx, o));
    float e = (lane < NCLS) ? __expf(l - mx) : 0.f;
    float sum = e;
#pragma unroll
    for (int o = 32; o > 0; o >>= 1) sum += __shfl_xor(sum, o);
    float ls = l - mx - __logf(sum);
    if (lane < NCLS) {
        size_t i0 = (size_t)node * NCLS + lane;
        size_t i1 = (size_t)N_NODES * NCLS + i0;
        if (flags[0]) {
            ((float*)out)[i0] = ls;
            ((float*)out)[i1] = l;
        } else {
            ((ushort*)out)[i0] = f2bf(ls);
            ((ushort*)out)[i1] = f2bf(l);
        }
    }
}

// ---------------- host ----------------

static inline size_t alup(size_t x) { return (x + 255) & ~(size_t)255; }

extern "C" void kernel_launch(void* const* d_in, const int* in_sizes, int n_in,
                              void* d_out, int out_size, void* d_ws, size_t ws_size,
                              hipStream_t stream) {
    char* w = (char*)d_ws;
    int* flags   = (int*)w;           w += alup(16);
    float* dinv  = (float*)w;         w += alup(N_NODES * 4);
    int* cnt     = (int*)w;           w += alup(N_NODES * 4);
    int* offs    = (int*)w;           w += alup(N_NODES * 4);
    int* woff    = (int*)w;           w += alup(N_NODES * 4);
    int* src32   = (int*)w;           w += alup(N_EDGES * 4);
    int* dst32   = (int*)w;           w += alup(N_EDGES * 4);
    int* csr     = (int*)w;           w += alup(N_EDGES * 4);
    ushort* xb   = (ushort*)w;        w += alup((size_t)N_NODES * HDIM * 2);
    ushort* wb[5]; ushort* bb[5];
    for (int l = 0; l < 5; ++l) {
        int wn = (l < 4) ? HDIM * HDIM : HDIM * NCLS;
        int bn = (l < 4) ? HDIM : NCLS;
        wb[l] = (ushort*)w; w += alup((size_t)wn * 2);
        bb[l] = (ushort*)w; w += alup((size_t)bn * 2);
    }
    ushort* tbuf = (ushort*)w;        w += alup((size_t)(N_NODES + 16) * HDIM * 2);
    ushort* hbuf = (ushort*)w;        w += alup((size_t)(N_NODES + 16) * HDIM * 2);
    float* t5    = (float*)w;         w += alup((size_t)N_NODES * NCLS * 4);

    detect_kernel<<<1, 64, 0, stream>>>(d_in[0], d_in[1], flags);

    PrepArgs pa;
    pa.x = d_in[0];
    pa.ei = d_in[1];
    int sizes[10] = { HDIM * HDIM, HDIM, HDIM * HDIM, HDIM, HDIM * HDIM, HDIM,
                      HDIM * HDIM, HDIM, HDIM * NCLS, NCLS };
    int run = 0;
    for (int t = 0; t < 10; ++t) {
        pa.wsrc[t] = d_in[2 + t];
        pa.wdst[t] = (t & 1) ? bb[t >> 1] : wb[t >> 1];
        pa.woffs[t] = run;
        run += sizes[t];
    }
    pa.woffs[10] = run;  // == WTOT
    pa.xb = xb; pa.src32 = src32; pa.dst32 = dst32; pa.cnt = cnt;
    pa.tbuf = tbuf; pa.hbuf = hbuf; pa.flags = flags;

    prep_kernel<<<PREP_TOTAL, 256, 0, stream>>>(pa);

    const int eblk = (N_EDGES + 255) / 256;   // 1250
    count_kernel<<<eblk, 256, 0, stream>>>(dst32, cnt);
    scan_dinv_kernel<<<1, 256, 0, stream>>>(cnt, offs, woff, dinv);
    fill_kernel<<<eblk, 256, 0, stream>>>(src32, dst32, woff, csr);

    const int aggblk = N_NODES / 4;  // 2500

    gemm256_kernel<<<dim3(8, 78), 256, 0, stream>>>(xb, wb[0], dinv, tbuf);
    agg256_kernel<<<dim3(aggblk, 2), 256, 0, stream>>>(tbuf, csr, offs, cnt, dinv, bb[0], hbuf);
    for (int l = 1; l < 4; ++l) {
        gemm256_kernel<<<dim3(8, 78), 256, 0, stream>>>(hbuf, wb[l], dinv, tbuf);
        agg256_kernel<<<dim3(aggblk, 2), 256, 0, stream>>>(tbuf, csr, offs, cnt, dinv, bb[l], hbuf);
    }
    gemm40_kernel<<<dim3(3, 80), 256, 0, stream>>>(hbuf, wb[4], dinv, t5);
    aggsoft_kernel<<<aggblk, 256, 0, stream>>>(t5, csr, offs, cnt, dinv, bb[4], d_out, flags);
}

// Round 8
// 298.319 us; speedup vs baseline: 3.8431x; 1.0613x over previous
//
#include <hip/hip_runtime.h>
#include <hip/hip_bf16.h>

#define N_NODES 10000
#define N_EDGES 320000
#define HDIM    256
#define NCLS    40

typedef __attribute__((ext_vector_type(8))) short short8;
typedef __attribute__((ext_vector_type(4))) float floatx4;
typedef unsigned long long ull;
typedef unsigned short ushort;

__device__ __forceinline__ float bf2f(ushort u) {
    union { unsigned int i; float f; } v; v.i = ((unsigned int)u) << 16; return v.f;
}
__device__ __forceinline__ ushort f2bf(float f) {
    __hip_bfloat16 h = __float2bfloat16(f);
    return *reinterpret_cast<ushort*>(&h);
}

// ---------------- K1: detect dtypes + zero cnt + zero sentinel rows ----------------
// flags[0]=1 if float tensors are fp32; flags[1]=1 if edge_index is int64

__global__ __launch_bounds__(256)
void init_kernel(const void* x, const void* ei, int* flags, int* cnt,
                 ushort* tbuf, ushort* hbuf) {
    const int b = blockIdx.x;
    const int tid = threadIdx.x;
    if (b < 40) {
        int i = b * 256 + tid;
        if (i < N_NODES) cnt[i] = 0;
    } else {
        if (tid < 64) {
            const int lane = tid;
            const ushort* u = (const ushort*)x;
            int e = (u[2 * lane] >> 7) & 0xFF;
            ull badmask = __ballot(e < 100 || e > 140);
            const int* ii = (const int*)ei;
            ull oddnz = __ballot(ii[2 * lane + 1] != 0);
            if (lane == 0) {
                flags[0] = (__popcll(badmask) >= 8) ? 1 : 0;
                flags[1] = (oddnz == 0) ? 1 : 0;
            }
        } else if (tid < 128) {
            ((ull*)(tbuf + (size_t)N_NODES * 256))[tid - 64] = 0;
        } else if (tid < 192) {
            ((ull*)(hbuf + (size_t)N_NODES * 256))[tid - 128] = 0;
        }
    }
}

// ---------------- K2: prep (x/W/b -> bf16, edges -> int32 + degree count) ----------------

struct PrepArgs {
    const void* x;
    const void* ei;
    const void* wsrc[10];
    ushort* wdst[10];
    int woffs[11];
    ushort* xb;
    int* src32;
    int* dst32;
    int* cnt;
    const int* flags;
};

#define PREP_XB 2500
#define PREP_WB 1069
#define PREP_EB 1250
#define PREP_TOTAL (PREP_XB + PREP_WB + PREP_EB)
#define WTOT 273448

__global__ __launch_bounds__(256)
void prep_kernel(PrepArgs a) {
    const int b = blockIdx.x;
    const int f32 = a.flags[0];
    if (b < PREP_XB) {
        int i4 = b * 256 + threadIdx.x;   // 2500*256 vec4 == 2,560,000 elements exactly
        if (f32) {
            float4 v = ((const float4*)a.x)[i4];
            ull p = (ull)f2bf(v.x) | ((ull)f2bf(v.y) << 16) |
                    ((ull)f2bf(v.z) << 32) | ((ull)f2bf(v.w) << 48);
            ((ull*)a.xb)[i4] = p;
        } else {
            ((ull*)a.xb)[i4] = ((const ull*)a.x)[i4];
        }
    } else if (b < PREP_XB + PREP_WB) {
        int i = (b - PREP_XB) * 256 + threadIdx.x;
        if (i < WTOT) {
            int t = 0;
#pragma unroll
            for (int k = 1; k < 10; ++k) t += (i >= a.woffs[k]);
            int local = i - a.woffs[t];
            ushort v;
            if (f32) v = f2bf(((const float*)a.wsrc[t])[local]);
            else     v = ((const ushort*)a.wsrc[t])[local];
            a.wdst[t][local] = v;
        }
    } else {
        int e = (b - PREP_XB - PREP_WB) * 256 + threadIdx.x;
        const int* ii = (const int*)a.ei;
        int s, d;
        if (a.flags[1]) { s = ii[2 * e]; d = ii[2 * (N_EDGES + e)]; }
        else            { s = ii[e];     d = ii[N_EDGES + e]; }
        s = ((unsigned)s < N_NODES) ? s : 0;
        d = ((unsigned)d < N_NODES) ? d : 0;
        a.src32[e] = s;
        a.dst32[e] = d;
        atomicAdd(&a.cnt[d], 1);   // cnt zeroed in init_kernel (prior dispatch)
    }
}

// ---------------- K3: scan + dinv ----------------

__global__ __launch_bounds__(256)
void scan_dinv_kernel(const int* __restrict__ cnt, int* __restrict__ offs,
                      int* __restrict__ woff, float* __restrict__ dinv) {
    __shared__ int part[256];
    const int t = threadIdx.x;
    const int CH = 40;  // 256*40 >= 10000
    const int base = t * CH;
    int s = 0;
    for (int j = 0; j < CH; ++j) {
        int i = base + j;
        if (i < N_NODES) s += cnt[i];
    }
    part[t] = s;
    __syncthreads();
    for (int off = 1; off < 256; off <<= 1) {
        int v = (t >= off) ? part[t - off] : 0;
        __syncthreads();
        part[t] += v;
        __syncthreads();
    }
    int run = (t == 0) ? 0 : part[t - 1];
    for (int j = 0; j < CH; ++j) {
        int i = base + j;
        if (i < N_NODES) {
            int c = cnt[i];
            offs[i] = run;
            woff[i] = run;
            dinv[i] = rsqrtf((float)c + 1.0f);
            run += c;
        }
    }
}

// ---------------- K4: CSR fill ----------------

__global__ void fill_kernel(const int* __restrict__ src, const int* __restrict__ dst,
                            int* __restrict__ woff, int* __restrict__ csr) {
    int e = blockIdx.x * 256 + threadIdx.x;
    if (e < N_EDGES) {
        int d = dst[e];
        int p = atomicAdd(&woff[d], 1);
        csr[p] = src[e];
    }
}

// ---------------- GEMM 256-wide: 2 col-tiles per wave, grid (8, 78) ----------------

__global__ __launch_bounds__(256)
void gemm256_kernel(const ushort* __restrict__ A, const ushort* __restrict__ W,
                    const float* __restrict__ dinv, ushort* __restrict__ T) {
    const int lane = threadIdx.x & 63;
    const int wave = threadIdx.x >> 6;
    const int m = lane & 15;
    const int quad = lane >> 4;
    const int c0 = blockIdx.x * 32;

    short8 bfrag[2][8];
#pragma unroll
    for (int t = 0; t < 2; ++t)
#pragma unroll
        for (int s = 0; s < 8; ++s)
#pragma unroll
            for (int j = 0; j < 8; ++j)
                bfrag[t][s][j] = (short)W[(size_t)(s * 32 + quad * 8 + j) * 256 + c0 + t * 16 + m];

    const int step = gridDim.y * 4;
    for (int rt = blockIdx.y * 4 + wave; rt < N_NODES / 16; rt += step) {
        const int r0 = rt * 16;
        floatx4 acc0 = {0.f, 0.f, 0.f, 0.f};
        floatx4 acc1 = {0.f, 0.f, 0.f, 0.f};
        const ushort* arow = A + (size_t)(r0 + m) * 256 + quad * 8;
#pragma unroll
        for (int s = 0; s < 8; ++s) {
            short8 af = *(const short8*)(arow + s * 32);
            acc0 = __builtin_amdgcn_mfma_f32_16x16x32_bf16(af, bfrag[0][s], acc0, 0, 0, 0);
            acc1 = __builtin_amdgcn_mfma_f32_16x16x32_bf16(af, bfrag[1][s], acc1, 0, 0, 0);
        }
#pragma unroll
        for (int r = 0; r < 4; ++r) {
            int row = r0 + quad * 4 + r;
            float di = dinv[row];
            T[(size_t)row * 256 + c0 + m]      = f2bf(acc0[r] * di);
            T[(size_t)row * 256 + c0 + 16 + m] = f2bf(acc1[r] * di);
        }
    }
}

// ---------------- GEMM 40-wide -> fp32 T5, grid (3, 80) ----------------

__global__ __launch_bounds__(256)
void gemm40_kernel(const ushort* __restrict__ A, const ushort* __restrict__ W,
                   const float* __restrict__ dinv, float* __restrict__ T) {
    const int lane = threadIdx.x & 63;
    const int wave = threadIdx.x >> 6;
    const int m = lane & 15;
    const int quad = lane >> 4;
    const int col = blockIdx.x * 16 + m;
    const bool colok = col < NCLS;

    short8 bfrag[8];
#pragma unroll
    for (int s = 0; s < 8; ++s)
#pragma unroll
        for (int j = 0; j < 8; ++j)
            bfrag[s][j] = colok ? (short)W[(size_t)(s * 32 + quad * 8 + j) * NCLS + col] : (short)0;

    const int step = gridDim.y * 4;
    for (int rt = blockIdx.y * 4 + wave; rt < N_NODES / 16; rt += step) {
        const int r0 = rt * 16;
        floatx4 acc = {0.f, 0.f, 0.f, 0.f};
        const ushort* arow = A + (size_t)(r0 + m) * 256 + quad * 8;
#pragma unroll
        for (int s = 0; s < 8; ++s) {
            short8 af = *(const short8*)(arow + s * 32);
            acc = __builtin_amdgcn_mfma_f32_16x16x32_bf16(af, bfrag[s], acc, 0, 0, 0);
        }
        if (colok) {
#pragma unroll
            for (int r = 0; r < 4; ++r) {
                int row = r0 + quad * 4 + r;
                T[(size_t)row * NCLS + col] = acc[r] * dinv[row];
            }
        }
    }
}

// ---------------- Aggregation 256-wide: dual-row 16B gathers, 8-deep (round-4 proven) ----------------

__device__ __forceinline__ void accum16(float* acc, int4 r) {
#pragma unroll
    for (int k = 0; k < 4; ++k) {
        union { int i; float f; } lo, hi;
        int d = (&r.x)[k];
        lo.i = d << 16;
        hi.i = d & 0xffff0000;
        acc[2 * k]     += lo.f;
        acc[2 * k + 1] += hi.f;
    }
}

__global__ __launch_bounds__(256)
void agg256_kernel(const ushort* __restrict__ T,
                   const int* __restrict__ csr, const int* __restrict__ offs,
                   const int* __restrict__ cnt, const float* __restrict__ dinv,
                   const ushort* __restrict__ bias,
                   ushort* __restrict__ H) {
    const int node = blockIdx.x * 4 + (threadIdx.x >> 6);
    const int lane = threadIdx.x & 63;
    const int half = lane >> 5;
    const int q = lane & 31;
    const int start = offs[node];
    const int count = cnt[node];
    const float di = dinv[node];

    float acc[8];
    {
        int sinit = half ? N_NODES : node;   // sentinel row = zeros
        int4 r = *(const int4*)(T + (size_t)sinit * 256 + q * 8);
#pragma unroll
        for (int k = 0; k < 4; ++k) {
            union { int i; float f; } lo, hi;
            int d = (&r.x)[k];
            lo.i = d << 16; hi.i = d & 0xffff0000;
            acc[2 * k] = lo.f; acc[2 * k + 1] = hi.f;
        }
    }

    for (int bj = 0; bj < count; bj += 64) {
        int mrem = count - bj;
        int mm = mrem < 64 ? mrem : 64;
        int idxv = (lane < mm) ? csr[start + bj + lane] : N_NODES;
        int j2 = 0;
        for (; j2 + 16 <= mm; j2 += 16) {
            int s[8];
#pragma unroll
            for (int k = 0; k < 8; ++k) s[k] = __shfl(idxv, j2 + 2 * k + half);
            int4 r[8];
#pragma unroll
            for (int k = 0; k < 8; ++k) r[k] = *(const int4*)(T + (size_t)s[k] * 256 + q * 8);
#pragma unroll
            for (int k = 0; k < 8; ++k) accum16(acc, r[k]);
        }
        for (; j2 < mm; j2 += 2) {
            int s = __shfl(idxv, j2 + half);
            int4 r = *(const int4*)(T + (size_t)s * 256 + q * 8);
            accum16(acc, r);
        }
    }

#pragma unroll
    for (int i = 0; i < 8; ++i) acc[i] += __shfl_xor(acc[i], 32);

    if (half == 0) {
        int4 bv = *(const int4*)(bias + q * 8);
        int out_d[4];
#pragma unroll
        for (int k = 0; k < 4; ++k) {
            union { int i; float f; } lo, hi;
            int d = (&bv.x)[k];
            lo.i = d << 16; hi.i = d & 0xffff0000;
            float v0 = fmaxf(acc[2 * k] * di + lo.f, 0.f);
            float v1 = fmaxf(acc[2 * k + 1] * di + hi.f, 0.f);
            out_d[k] = (int)f2bf(v0) | ((int)f2bf(v1) << 16);
        }
        *(int4*)(H + (size_t)node * 256 + q * 8) = *(int4*)out_d;
    }
}

// ---------------- Aggregation 40-wide + log_softmax + output writes, fused ----------------

__global__ __launch_bounds__(256)
void aggsoft_kernel(const float* __restrict__ T,
                    const int* __restrict__ csr, const int* __restrict__ offs,
                    const int* __restrict__ cnt, const float* __restrict__ dinv,
                    const ushort* __restrict__ bias,
                    void* __restrict__ out, const int* __restrict__ flags) {
    const int node = blockIdx.x * 4 + (threadIdx.x >> 6);
    const int lane = threadIdx.x & 63;
    const int start = offs[node];
    const int count = cnt[node];
    const float di = dinv[node];

    float acc = (lane < NCLS) ? T[(size_t)node * NCLS + lane] : 0.f;
    for (int bj = 0; bj < count; bj += 64) {
        int mrem = count - bj;
        int mm = mrem < 64 ? mrem : 64;
        int idxv = (lane < mm) ? csr[start + bj + lane] : 0;
        int jj = 0;
        for (; jj + 4 <= mm; jj += 4) {
            int s0 = __shfl(idxv, jj + 0);
            int s1 = __shfl(idxv, jj + 1);
            int s2 = __shfl(idxv, jj + 2);
            int s3 = __shfl(idxv, jj + 3);
            if (lane < NCLS) {
                float t0 = T[(size_t)s0 * NCLS + lane];
                float t1 = T[(size_t)s1 * NCLS + lane];
                float t2 = T[(size_t)s2 * NCLS + lane];
                float t3 = T[(size_t)s3 * NCLS + lane];
                acc += t0 + t1 + t2 + t3;
            }
        }
        for (; jj < mm; ++jj) {
            int s = __shfl(idxv, jj);
            if (lane < NCLS) acc += T[(size_t)s * NCLS + lane];
        }
    }

    float l = (lane < NCLS) ? (acc * di + bf2f(bias[lane])) : -INFINITY;
    float mx = l;
#pragma unroll
    for (int o = 32; o > 0; o >>= 1) mx = fmaxf(mx, __shfl_xor(mx, o));
    float e = (lane < NCLS) ? __expf(l - mx) : 0.f;
    float sum = e;
#pragma unroll
    for (int o = 32; o > 0; o >>= 1) sum += __shfl_xor(sum, o);
    float ls = l - mx - __logf(sum);
    if (lane < NCLS) {
        size_t i0 = (size_t)node * NCLS + lane;
        size_t i1 = (size_t)N_NODES * NCLS + i0;
        if (flags[0]) {
            ((float*)out)[i0] = ls;
            ((float*)out)[i1] = l;
        } else {
            ((ushort*)out)[i0] = f2bf(ls);
            ((ushort*)out)[i1] = f2bf(l);
        }
    }
}

// ---------------- host ----------------

static inline size_t alup(size_t x) { return (x + 255) & ~(size_t)255; }

extern "C" void kernel_launch(void* const* d_in, const int* in_sizes, int n_in,
                              void* d_out, int out_size, void* d_ws, size_t ws_size,
                              hipStream_t stream) {
    char* w = (char*)d_ws;
    int* flags   = (int*)w;           w += alup(16);
    float* dinv  = (float*)w;         w += alup(N_NODES * 4);
    int* cnt     = (int*)w;           w += alup(N_NODES * 4);
    int* offs    = (int*)w;           w += alup(N_NODES * 4);
    int* woff    = (int*)w;           w += alup(N_NODES * 4);
    int* src32   = (int*)w;           w += alup(N_EDGES * 4);
    int* dst32   = (int*)w;           w += alup(N_EDGES * 4);
    int* csr     = (int*)w;           w += alup(N_EDGES * 4);
    ushort* xb   = (ushort*)w;        w += alup((size_t)N_NODES * HDIM * 2);
    ushort* wb[5]; ushort* bb[5];
    for (int l = 0; l < 5; ++l) {
        int wn = (l < 4) ? HDIM * HDIM : HDIM * NCLS;
        int bn = (l < 4) ? HDIM : NCLS;
        wb[l] = (ushort*)w; w += alup((size_t)wn * 2);
        bb[l] = (ushort*)w; w += alup((size_t)bn * 2);
    }
    ushort* tbuf = (ushort*)w;        w += alup((size_t)(N_NODES + 16) * HDIM * 2);
    ushort* hbuf = (ushort*)w;        w += alup((size_t)(N_NODES + 16) * HDIM * 2);
    float* t5    = (float*)w;         w += alup((size_t)N_NODES * NCLS * 4);

    // K1: detect + zero cnt + zero sentinels
    init_kernel<<<41, 256, 0, stream>>>(d_in[0], d_in[1], flags, cnt, tbuf, hbuf);

    // K2: prep + degree count
    PrepArgs pa;
    pa.x = d_in[0];
    pa.ei = d_in[1];
    int sizes[10] = { HDIM * HDIM, HDIM, HDIM * HDIM, HDIM, HDIM * HDIM, HDIM,
                      HDIM * HDIM, HDIM, HDIM * NCLS, NCLS };
    int run = 0;
    for (int t = 0; t < 10; ++t) {
        pa.wsrc[t] = d_in[2 + t];
        pa.wdst[t] = (t & 1) ? bb[t >> 1] : wb[t >> 1];
        pa.woffs[t] = run;
        run += sizes[t];
    }
    pa.woffs[10] = run;  // == WTOT
    pa.xb = xb; pa.src32 = src32; pa.dst32 = dst32; pa.cnt = cnt; pa.flags = flags;
    prep_kernel<<<PREP_TOTAL, 256, 0, stream>>>(pa);

    // K3/K4: scan + fill
    scan_dinv_kernel<<<1, 256, 0, stream>>>(cnt, offs, woff, dinv);
    const int eblk = (N_EDGES + 255) / 256;   // 1250
    fill_kernel<<<eblk, 256, 0, stream>>>(src32, dst32, woff, csr);

    const int aggblk = N_NODES / 4;  // 2500

    // layers
    gemm256_kernel<<<dim3(8, 78), 256, 0, stream>>>(xb, wb[0], dinv, tbuf);
    agg256_kernel<<<aggblk, 256, 0, stream>>>(tbuf, csr, offs, cnt, dinv, bb[0], hbuf);
    for (int l = 1; l < 4; ++l) {
        gemm256_kernel<<<dim3(8, 78), 256, 0, stream>>>(hbuf, wb[l], dinv, tbuf);
        agg256_kernel<<<aggblk, 256, 0, stream>>>(tbuf, csr, offs, cnt, dinv, bb[l], hbuf);
    }
    gemm40_kernel<<<dim3(3, 80), 256, 0, stream>>>(hbuf, wb[4], dinv, t5);
    aggsoft_kernel<<<aggblk, 256, 0, stream>>>(t5, csr, offs, cnt, dinv, bb[4], d_out, flags);
}

// Round 9
// 282.375 us; speedup vs baseline: 4.0601x; 1.0565x over previous
//
#include <hip/hip_runtime.h>
#include <hip/hip_bf16.h>

#define N_NODES 10000
#define N_EDGES 320000
#define HDIM    256
#define NCLS    40

typedef __attribute__((ext_vector_type(8))) short short8;
typedef __attribute__((ext_vector_type(4))) float floatx4;
typedef unsigned long long ull;
typedef unsigned short ushort;

__device__ __forceinline__ float bf2f(ushort u) {
    union { unsigned int i; float f; } v; v.i = ((unsigned int)u) << 16; return v.f;
}
__device__ __forceinline__ ushort f2bf(float f) {
    __hip_bfloat16 h = __float2bfloat16(f);
    return *reinterpret_cast<ushort*>(&h);
}

// packed-W sizes (ushorts): W2/W3/W4: 16 tiles * 8 s * 4 quad * 16 m * 8 j = 65536
//                           W5: 3 tiles (cols padded to 48) = 24576
#define WP256 65536
#define WP40  24576

// ---------------- K1: detect dtypes + zero cnt + zero sentinels + zero wp5 ----------------

__global__ __launch_bounds__(256)
void init_kernel(const void* x, const void* ei, int* flags, int* cnt,
                 ushort* tA, ushort* tB, ushort* wp5) {
    const int b = blockIdx.x;
    const int tid = threadIdx.x;
    if (b < 40) {
        int i = b * 256 + tid;
        if (i < N_NODES) cnt[i] = 0;
    } else if (b == 40) {
        if (tid < 64) {
            const int lane = tid;
            const ushort* u = (const ushort*)x;
            int e = (u[2 * lane] >> 7) & 0xFF;
            ull badmask = __ballot(e < 100 || e > 140);
            const int* ii = (const int*)ei;
            ull oddnz = __ballot(ii[2 * lane + 1] != 0);
            if (lane == 0) {
                flags[0] = (__popcll(badmask) >= 8) ? 1 : 0;
                flags[1] = (oddnz == 0) ? 1 : 0;
            }
        } else if (tid < 128) {
            ((ull*)(tA + (size_t)N_NODES * 256))[tid - 64] = 0;
        } else if (tid < 192) {
            ((ull*)(tB + (size_t)N_NODES * 256))[tid - 128] = 0;
        }
    } else {
        int i = (b - 41) * 256 + tid;          // zero wp5 (pad cols 40..47)
        if (i < WP40 / 4) ((ull*)wp5)[i] = 0;
    }
}

// ---------------- K2: prep (x/W/b -> bf16, W2..W5 -> packed frags, edges -> int32) ----------------

struct PrepArgs {
    const void* x;
    const void* ei;
    const void* wsrc[10];
    ushort* wdst[10];
    int woffs[11];
    ushort* wp[4];     // packed W2..W5
    ushort* xb;
    int* src32;
    int* dst32;
    const int* flags;
};

#define PREP_XB 2500
#define PREP_WB 1069
#define PREP_EB 1250
#define PREP_TOTAL (PREP_XB + PREP_WB + PREP_EB)
#define WTOT 273448

__global__ __launch_bounds__(256)
void prep_kernel(PrepArgs a) {
    const int b = blockIdx.x;
    const int f32 = a.flags[0];
    if (b < PREP_XB) {
        int i4 = b * 256 + threadIdx.x;   // 2500*256 vec4 == 2,560,000 elements exactly
        if (f32) {
            float4 v = ((const float4*)a.x)[i4];
            ull p = (ull)f2bf(v.x) | ((ull)f2bf(v.y) << 16) |
                    ((ull)f2bf(v.z) << 32) | ((ull)f2bf(v.w) << 48);
            ((ull*)a.xb)[i4] = p;
        } else {
            ((ull*)a.xb)[i4] = ((const ull*)a.x)[i4];
        }
    } else if (b < PREP_XB + PREP_WB) {
        int i = (b - PREP_XB) * 256 + threadIdx.x;
        if (i < WTOT) {
            int t = 0;
#pragma unroll
            for (int k = 1; k < 10; ++k) t += (i >= a.woffs[k]);
            int local = i - a.woffs[t];
            ushort v;
            if (f32) v = f2bf(((const float*)a.wsrc[t])[local]);
            else     v = ((const ushort*)a.wsrc[t])[local];
            a.wdst[t][local] = v;
            if ((t & 1) == 0 && t >= 2) {
                // weight W(wnum+1), wnum = t/2 in 1..4 -> pack into wp[wnum-1]
                int wnum = t >> 1;
                int dout = (wnum < 4) ? 256 : NCLS;
                int k = local / dout;
                int col = local - k * dout;
                int tile = col >> 4, m = col & 15;
                int s = k >> 5, quad = (k >> 3) & 3, j = k & 7;
                int pidx = ((((tile * 8 + s) * 4 + quad) * 16 + m) << 3) + j;
                a.wp[wnum - 1][pidx] = v;
            }
        }
    } else {
        int e = (b - PREP_XB - PREP_WB) * 256 + threadIdx.x;
        const int* ii = (const int*)a.ei;
        int s, d;
        if (a.flags[1]) { s = ii[2 * e]; d = ii[2 * (N_EDGES + e)]; }
        else            { s = ii[e];     d = ii[N_EDGES + e]; }
        a.src32[e] = ((unsigned)s < N_NODES) ? s : 0;
        a.dst32[e] = ((unsigned)d < N_NODES) ? d : 0;
    }
}

// ---------------- K3: degree count ----------------

__global__ void count_kernel(const int* __restrict__ dst, int* __restrict__ cnt) {
    int e = blockIdx.x * 256 + threadIdx.x;
    if (e < N_EDGES) atomicAdd(&cnt[dst[e]], 1);
}

// ---------------- K4: scan + dinv ----------------

__global__ __launch_bounds__(256)
void scan_dinv_kernel(const int* __restrict__ cnt, int* __restrict__ offs,
                      int* __restrict__ woff, float* __restrict__ dinv) {
    __shared__ int part[256];
    const int t = threadIdx.x;
    const int CH = 40;
    const int base = t * CH;
    int s = 0;
    for (int j = 0; j < CH; ++j) {
        int i = base + j;
        if (i < N_NODES) s += cnt[i];
    }
    part[t] = s;
    __syncthreads();
    for (int off = 1; off < 256; off <<= 1) {
        int v = (t >= off) ? part[t - off] : 0;
        __syncthreads();
        part[t] += v;
        __syncthreads();
    }
    int run = (t == 0) ? 0 : part[t - 1];
    for (int j = 0; j < CH; ++j) {
        int i = base + j;
        if (i < N_NODES) {
            int c = cnt[i];
            offs[i] = run;
            woff[i] = run;
            dinv[i] = rsqrtf((float)c + 1.0f);
            run += c;
        }
    }
}

// ---------------- K5: CSR fill ----------------

__global__ void fill_kernel(const int* __restrict__ src, const int* __restrict__ dst,
                            int* __restrict__ woff, int* __restrict__ csr) {
    int e = blockIdx.x * 256 + threadIdx.x;
    if (e < N_EDGES) {
        int d = dst[e];
        int p = atomicAdd(&woff[d], 1);
        csr[p] = src[e];
    }
}

// ---------------- GEMM1 (x@W1)*dinv -> tA, grid (8, 78) ----------------

__global__ __launch_bounds__(256)
void gemm256_kernel(const ushort* __restrict__ A, const ushort* __restrict__ W,
                    const float* __restrict__ dinv, ushort* __restrict__ T) {
    const int lane = threadIdx.x & 63;
    const int wave = threadIdx.x >> 6;
    const int m = lane & 15;
    const int quad = lane >> 4;
    const int c0 = blockIdx.x * 32;

    short8 bfrag[2][8];
#pragma unroll
    for (int t = 0; t < 2; ++t)
#pragma unroll
        for (int s = 0; s < 8; ++s)
#pragma unroll
            for (int j = 0; j < 8; ++j)
                bfrag[t][s][j] = (short)W[(size_t)(s * 32 + quad * 8 + j) * 256 + c0 + t * 16 + m];

    const int step = gridDim.y * 4;
    for (int rt = blockIdx.y * 4 + wave; rt < N_NODES / 16; rt += step) {
        const int r0 = rt * 16;
        floatx4 acc0 = {0.f, 0.f, 0.f, 0.f};
        floatx4 acc1 = {0.f, 0.f, 0.f, 0.f};
        const ushort* arow = A + (size_t)(r0 + m) * 256 + quad * 8;
#pragma unroll
        for (int s = 0; s < 8; ++s) {
            short8 af = *(const short8*)(arow + s * 32);
            acc0 = __builtin_amdgcn_mfma_f32_16x16x32_bf16(af, bfrag[0][s], acc0, 0, 0, 0);
            acc1 = __builtin_amdgcn_mfma_f32_16x16x32_bf16(af, bfrag[1][s], acc1, 0, 0, 0);
        }
#pragma unroll
        for (int r = 0; r < 4; ++r) {
            int row = r0 + quad * 4 + r;
            float di = dinv[row];
            T[(size_t)row * 256 + c0 + m]      = f2bf(acc0[r] * di);
            T[(size_t)row * 256 + c0 + 16 + m] = f2bf(acc1[r] * di);
        }
    }
}

// ---------------- fused agg + next-layer GEMM ----------------
// Block = 4 waves, 4 nodes. Phase A: round-4 dual-row gather -> h rows (bf16) in LDS.
// Phase B: 16x16x32 MFMA slab over the 4 valid rows (rows 4-15 garbage, never stored).

#define HROW 264   // LDS row stride in ushorts (528 B)

__device__ __forceinline__ void accum16(float* acc, int4 r) {
#pragma unroll
    for (int k = 0; k < 4; ++k) {
        union { int i; float f; } lo, hi;
        int d = (&r.x)[k];
        lo.i = d << 16;
        hi.i = d & 0xffff0000;
        acc[2 * k]     += lo.f;
        acc[2 * k + 1] += hi.f;
    }
}

// gather one node's h-row (relu(acc*di+bias)) into LDS row `wave` (half-0 lanes write)
__device__ __forceinline__ void gather_to_lds(const ushort* __restrict__ T,
                                              const int* __restrict__ csr,
                                              const int* __restrict__ offs,
                                              const int* __restrict__ cnt,
                                              const float* __restrict__ dinv,
                                              const ushort* __restrict__ bias,
                                              ushort* hs, int node, int lane, int wave) {
    const int half = lane >> 5;
    const int q = lane & 31;
    const int start = offs[node];
    const int count = cnt[node];
    const float di = dinv[node];

    float acc[8];
    {
        int sinit = half ? N_NODES : node;
        int4 r = *(const int4*)(T + (size_t)sinit * 256 + q * 8);
#pragma unroll
        for (int k = 0; k < 4; ++k) {
            union { int i; float f; } lo, hi;
            int d = (&r.x)[k];
            lo.i = d << 16; hi.i = d & 0xffff0000;
            acc[2 * k] = lo.f; acc[2 * k + 1] = hi.f;
        }
    }

    for (int bj = 0; bj < count; bj += 64) {
        int mrem = count - bj;
        int mm = mrem < 64 ? mrem : 64;
        int idxv = (lane < mm) ? csr[start + bj + lane] : N_NODES;
        int j2 = 0;
        for (; j2 + 16 <= mm; j2 += 16) {
            int s[8];
#pragma unroll
            for (int k = 0; k < 8; ++k) s[k] = __shfl(idxv, j2 + 2 * k + half);
            int4 r[8];
#pragma unroll
            for (int k = 0; k < 8; ++k) r[k] = *(const int4*)(T + (size_t)s[k] * 256 + q * 8);
#pragma unroll
            for (int k = 0; k < 8; ++k) accum16(acc, r[k]);
        }
        for (; j2 < mm; j2 += 2) {
            int s = __shfl(idxv, j2 + half);
            int4 r = *(const int4*)(T + (size_t)s * 256 + q * 8);
            accum16(acc, r);
        }
    }

#pragma unroll
    for (int i = 0; i < 8; ++i) acc[i] += __shfl_xor(acc[i], 32);

    if (half == 0) {
        int4 bv = *(const int4*)(bias + q * 8);
        int out_d[4];
#pragma unroll
        for (int k = 0; k < 4; ++k) {
            union { int i; float f; } lo, hi;
            int d = (&bv.x)[k];
            lo.i = d << 16; hi.i = d & 0xffff0000;
            float v0 = fmaxf(acc[2 * k] * di + lo.f, 0.f);
            float v1 = fmaxf(acc[2 * k + 1] * di + hi.f, 0.f);
            out_d[k] = (int)f2bf(v0) | ((int)f2bf(v1) << 16);
        }
        *(int4*)(hs + wave * HROW + q * 8) = *(int4*)out_d;
    }
}

__global__ __launch_bounds__(256)
void fused256_kernel(const ushort* __restrict__ Tin, const ushort* __restrict__ Wp,
                     const ushort* __restrict__ bias, const float* __restrict__ dinv,
                     const int* __restrict__ csr, const int* __restrict__ offs,
                     const int* __restrict__ cnt, ushort* __restrict__ Tout) {
    __shared__ ushort hs[16 * HROW];
    const int tid = threadIdx.x;
    const int lane = tid & 63;
    const int wave = tid >> 6;
    const int m = lane & 15;
    const int quad = lane >> 4;
    const int nb = blockIdx.x * 4;

    gather_to_lds(Tin, csr, offs, cnt, dinv, bias, hs, nb + wave, lane, wave);
    __syncthreads();

    float d0 = dinv[nb], d1 = dinv[nb + 1], d2 = dinv[nb + 2], d3 = dinv[nb + 3];
    float dv[4] = {d0, d1, d2, d3};

#pragma unroll
    for (int tt = 0; tt < 4; ++tt) {
        const int tile = wave * 4 + tt;
        short8 bfrag[8];
#pragma unroll
        for (int s = 0; s < 8; ++s)
            bfrag[s] = *(const short8*)(Wp + ((((tile * 8 + s) * 4 + quad) * 16 + m) << 3));
        floatx4 acc = {0.f, 0.f, 0.f, 0.f};
#pragma unroll
        for (int s = 0; s < 8; ++s) {
            short8 af = *(const short8*)(hs + m * HROW + s * 32 + quad * 8);
            acc = __builtin_amdgcn_mfma_f32_16x16x32_bf16(af, bfrag[s], acc, 0, 0, 0);
        }
        if (quad == 0) {
#pragma unroll
            for (int r = 0; r < 4; ++r)
                Tout[(size_t)(nb + r) * 256 + tile * 16 + m] = f2bf(acc[r] * dv[r]);
        }
    }
}

// fused final: agg(t4) -> h4 in LDS -> h4 @ W5 * dinv -> t5 (fp32, 40 cols)

__global__ __launch_bounds__(256)
void fused40_kernel(const ushort* __restrict__ Tin, const ushort* __restrict__ Wp,
                    const ushort* __restrict__ bias, const float* __restrict__ dinv,
                    const int* __restrict__ csr, const int* __restrict__ offs,
                    const int* __restrict__ cnt, float* __restrict__ T5) {
    __shared__ ushort hs[16 * HROW];
    const int tid = threadIdx.x;
    const int lane = tid & 63;
    const int wave = tid >> 6;
    const int m = lane & 15;
    const int quad = lane >> 4;
    const int nb = blockIdx.x * 4;

    gather_to_lds(Tin, csr, offs, cnt, dinv, bias, hs, nb + wave, lane, wave);
    __syncthreads();

    if (wave < 3) {
        const int tile = wave;
        const int col = tile * 16 + m;
        float dv[4] = {dinv[nb], dinv[nb + 1], dinv[nb + 2], dinv[nb + 3]};
        short8 bfrag[8];
#pragma unroll
        for (int s = 0; s < 8; ++s)
            bfrag[s] = *(const short8*)(Wp + ((((tile * 8 + s) * 4 + quad) * 16 + m) << 3));
        floatx4 acc = {0.f, 0.f, 0.f, 0.f};
#pragma unroll
        for (int s = 0; s < 8; ++s) {
            short8 af = *(const short8*)(hs + m * HROW + s * 32 + quad * 8);
            acc = __builtin_amdgcn_mfma_f32_16x16x32_bf16(af, bfrag[s], acc, 0, 0, 0);
        }
        if (quad == 0 && col < NCLS) {
#pragma unroll
            for (int r = 0; r < 4; ++r)
                T5[(size_t)(nb + r) * NCLS + col] = acc[r] * dv[r];
        }
    }
}

// ---------------- Aggregation 40-wide + log_softmax + output writes, fused ----------------

__global__ __launch_bounds__(256)
void aggsoft_kernel(const float* __restrict__ T,
                    const int* __restrict__ csr, const int* __restrict__ offs,
                    const int* __restrict__ cnt, const float* __restrict__ dinv,
                    const ushort* __restrict__ bias,
                    void* __restrict__ out, const int* __restrict__ flags) {
    const int node = blockIdx.x * 4 + (threadIdx.x >> 6);
    const int lane = threadIdx.x & 63;
    const int start = offs[node];
    const int count = cnt[node];
    const float di = dinv[node];

    float acc = (lane < NCLS) ? T[(size_t)node * NCLS + lane] : 0.f;
    for (int bj = 0; bj < count; bj += 64) {
        int mrem = count - bj;
        int mm = mrem < 64 ? mrem : 64;
        int idxv = (lane < mm) ? csr[start + bj + lane] : 0;
        int jj = 0;
        for (; jj + 4 <= mm; jj += 4) {
            int s0 = __shfl(idxv, jj + 0);
            int s1 = __shfl(idxv, jj + 1);
            int s2 = __shfl(idxv, jj + 2);
            int s3 = __shfl(idxv, jj + 3);
            if (lane < NCLS) {
                float t0 = T[(size_t)s0 * NCLS + lane];
                float t1 = T[(size_t)s1 * NCLS + lane];
                float t2 = T[(size_t)s2 * NCLS + lane];
                float t3 = T[(size_t)s3 * NCLS + lane];
                acc += t0 + t1 + t2 + t3;
            }
        }
        for (; jj < mm; ++jj) {
            int s = __shfl(idxv, jj);
            if (lane < NCLS) acc += T[(size_t)s * NCLS + lane];
        }
    }

    float l = (lane < NCLS) ? (acc * di + bf2f(bias[lane])) : -INFINITY;
    float mx = l;
#pragma unroll
    for (int o = 32; o > 0; o >>= 1) mx = fmaxf(mx, __shfl_xor(mx, o));
    float e = (lane < NCLS) ? __expf(l - mx) : 0.f;
    float sum = e;
#pragma unroll
    for (int o = 32; o > 0; o >>= 1) sum += __shfl_xor(sum, o);
    float ls = l - mx - __logf(sum);
    if (lane < NCLS) {
        size_t i0 = (size_t)node * NCLS + lane;
        size_t i1 = (size_t)N_NODES * NCLS + i0;
        if (flags[0]) {
            ((float*)out)[i0] = ls;
            ((float*)out)[i1] = l;
        } else {
            ((ushort*)out)[i0] = f2bf(ls);
            ((ushort*)out)[i1] = f2bf(l);
        }
    }
}

// ---------------- host ----------------

static inline size_t alup(size_t x) { return (x + 255) & ~(size_t)255; }

extern "C" void kernel_launch(void* const* d_in, const int* in_sizes, int n_in,
                              void* d_out, int out_size, void* d_ws, size_t ws_size,
                              hipStream_t stream) {
    char* w = (char*)d_ws;
    int* flags   = (int*)w;           w += alup(16);
    float* dinv  = (float*)w;         w += alup(N_NODES * 4);
    int* cnt     = (int*)w;           w += alup(N_NODES * 4);
    int* offs    = (int*)w;           w += alup(N_NODES * 4);
    int* woff    = (int*)w;           w += alup(N_NODES * 4);
    int* src32   = (int*)w;           w += alup(N_EDGES * 4);
    int* dst32   = (int*)w;           w += alup(N_EDGES * 4);
    int* csr     = (int*)w;           w += alup(N_EDGES * 4);
    ushort* xb   = (ushort*)w;        w += alup((size_t)N_NODES * HDIM * 2);
    ushort* wb[5]; ushort* bb[5];
    for (int l = 0; l < 5; ++l) {
        int wn = (l < 4) ? HDIM * HDIM : HDIM * NCLS;
        int bn = (l < 4) ? HDIM : NCLS;
        wb[l] = (ushort*)w; w += alup((size_t)wn * 2);
        bb[l] = (ushort*)w; w += alup((size_t)bn * 2);
    }
    ushort* wp[4];
    for (int i = 0; i < 4; ++i) {
        int n = (i < 3) ? WP256 : WP40;
        wp[i] = (ushort*)w; w += alup((size_t)n * 2);
    }
    ushort* tA = (ushort*)w;          w += alup((size_t)(N_NODES + 16) * HDIM * 2);
    ushort* tB = (ushort*)w;          w += alup((size_t)(N_NODES + 16) * HDIM * 2);
    float* t5  = (float*)w;           w += alup((size_t)N_NODES * NCLS * 4);

    // K1
    init_kernel<<<41 + (WP40 / 4 + 255) / 256, 256, 0, stream>>>(
        d_in[0], d_in[1], flags, cnt, tA, tB, wp[3]);

    // K2
    PrepArgs pa;
    pa.x = d_in[0];
    pa.ei = d_in[1];
    int sizes[10] = { HDIM * HDIM, HDIM, HDIM * HDIM, HDIM, HDIM * HDIM, HDIM,
                      HDIM * HDIM, HDIM, HDIM * NCLS, NCLS };
    int run = 0;
    for (int t = 0; t < 10; ++t) {
        pa.wsrc[t] = d_in[2 + t];
        pa.wdst[t] = (t & 1) ? bb[t >> 1] : wb[t >> 1];
        pa.woffs[t] = run;
        run += sizes[t];
    }
    pa.woffs[10] = run;  // == WTOT
    for (int i = 0; i < 4; ++i) pa.wp[i] = wp[i];
    pa.xb = xb; pa.src32 = src32; pa.dst32 = dst32; pa.flags = flags;
    prep_kernel<<<PREP_TOTAL, 256, 0, stream>>>(pa);

    // K3-K5
    const int eblk = (N_EDGES + 255) / 256;   // 1250
    count_kernel<<<eblk, 256, 0, stream>>>(dst32, cnt);
    scan_dinv_kernel<<<1, 256, 0, stream>>>(cnt, offs, woff, dinv);
    fill_kernel<<<eblk, 256, 0, stream>>>(src32, dst32, woff, csr);

    const int aggblk = N_NODES / 4;  // 2500

    // layers: gemm1 then fused agg+gemm chain
    gemm256_kernel<<<dim3(8, 78), 256, 0, stream>>>(xb, wb[0], dinv, tA);
    fused256_kernel<<<aggblk, 256, 0, stream>>>(tA, wp[0], bb[0], dinv, csr, offs, cnt, tB);
    fused256_kernel<<<aggblk, 256, 0, stream>>>(tB, wp[1], bb[1], dinv, csr, offs, cnt, tA);
    fused256_kernel<<<aggblk, 256, 0, stream>>>(tA, wp[2], bb[2], dinv, csr, offs, cnt, tB);
    fused40_kernel<<<aggblk, 256, 0, stream>>>(tB, wp[3], bb[3], dinv, csr, offs, cnt, t5);
    aggsoft_kernel<<<aggblk, 256, 0, stream>>>(t5, csr, offs, cnt, dinv, bb[4], d_out, flags);
}